// Round 1
// baseline (261.277 us; speedup 1.0000x reference)
//
#include <hip/hip_runtime.h>

// rel_pos_bias: out[m,n] = <rope(a,m), rope(b,n)> = g(m-n)  (Toeplitz!)
// g(d) = sum_j P_j*cos(d*f_j) + Q_j*sin(d*f_j),
//   P_j = a1[j]b1[j] + a2[j]b2[j],  Q_j = a1[j]b2[j] - a2[j]b1[j],
//   f_j = 10000^(-j/64)
// Kernel A computes g (16383 floats, uses sin odd / cos even symmetry).
// Kernel B streams the 8192x8192 f32 output (write-BW bound, ~41us floor).

#define CSEQ 8192
#define HALF 64
#define GOFF (CSEQ - 1)   // center index into g, g has 2*CSEQ-1 = 16383 entries

__global__ __launch_bounds__(256) void compute_g_kernel(
    const float* __restrict__ a, const float* __restrict__ b,
    float* __restrict__ g) {
    int d = blockIdx.x * blockDim.x + threadIdx.x;   // 0 .. 8191
    if (d >= CSEQ) return;
    float sP = 0.0f;  // sum P_j * cos(d*f_j)   (even in d)
    float sQ = 0.0f;  // sum Q_j * sin(d*f_j)   (odd in d)
    const float df = (float)d;
    #pragma unroll 8
    for (int j = 0; j < HALF; ++j) {
        float a1 = a[j], a2 = a[j + HALF];
        float b1 = b[j], b2 = b[j + HALF];
        float P = a1 * b1 + a2 * b2;
        float Q = a1 * b2 - a2 * b1;
        // f_j = 10000^(-j/64) = 2^(-j * log2(10000)/64)
        float f = exp2f(-0.20762050593046014f * (float)j);
        float s, c;
        sincosf(df * f, &s, &c);   // accurate OCML path (full range reduction)
        sP = fmaf(P, c, sP);
        sQ = fmaf(Q, s, sQ);
    }
    g[GOFF + d] = sP + sQ;
    g[GOFF - d] = sP - sQ;   // d=0 writes the same value twice, harmless
}

__global__ __launch_bounds__(256) void fill_out_kernel(
    const float* __restrict__ g, float* __restrict__ out) {
    unsigned tid = blockIdx.x * blockDim.x + threadIdx.x;
    unsigned m  = tid >> 11;            // row (8192 cols / 4 per thread = 2048 float4/row)
    unsigned n0 = (tid & 2047u) << 2;   // first col of this thread's float4
    // out[m, n0+k] = g[(m - (n0+k)) + GOFF], k = 0..3 (descending g index)
    const float* gp = g + (int)(GOFF + m - n0);
    float4 v;
    v.x = gp[0];
    v.y = gp[-1];
    v.z = gp[-2];
    v.w = gp[-3];
    *reinterpret_cast<float4*>(out + (size_t)m * CSEQ + n0) = v;
}

extern "C" void kernel_launch(void* const* d_in, const int* in_sizes, int n_in,
                              void* d_out, int out_size, void* d_ws, size_t ws_size,
                              hipStream_t stream) {
    const float* a = (const float*)d_in[0];
    const float* b = (const float*)d_in[1];
    // d_in[2] is the scalar c = 8192 (fixed by setup_inputs; hardcoded).
    float* g   = (float*)d_ws;     // needs 16383 * 4 B = 64 KiB of workspace
    float* out = (float*)d_out;    // 8192*8192 f32

    compute_g_kernel<<<CSEQ / 256, 256, 0, stream>>>(a, b, g);

    const unsigned total4 = (CSEQ * CSEQ) / 4;          // 16,777,216 float4s
    fill_out_kernel<<<total4 / 256, 256, 0, stream>>>(g, out);
}

// Round 2
// 254.023 us; speedup vs baseline: 1.0286x; 1.0286x over previous
//
#include <hip/hip_runtime.h>

// rel_pos_bias: out[m,n] = <rope(a,m), rope(b,n)> = g(m-n)  (Toeplitz!)
// g(d) = sum_j P_j*cos(d*f_j) + Q_j*sin(d*f_j),
//   P_j = a1[j]b1[j] + a2[j]b2[j],  Q_j = a1[j]b2[j] - a2[j]b1[j],
//   f_j = 10000^(-j/64)
//
// Kernel A: one WAVE per d (lane j = frequency j, single sincosf/thread,
//           butterfly reduce) -> no sequential sincosf chain, full-GPU TLP.
// Kernel B: LDS-staged Toeplitz broadcast. Stage the 4 KiB g-window with
//           ascending coalesced loads, reverse via stride -1 LDS writes
//           (conflict-free), read back as aligned ds_read_b128, float4 store.

#define CSEQ 8192
#define HALF 64
#define GOFF (CSEQ - 1)   // center index into g; g has 2*CSEQ-1 = 16383 entries

__global__ __launch_bounds__(256) void compute_g_kernel(
    const float* __restrict__ a, const float* __restrict__ b,
    float* __restrict__ g) {
    const int lane = threadIdx.x & 63;
    const int d    = blockIdx.x * 4 + (threadIdx.x >> 6);   // one wave per d
    const int j    = lane;                                   // frequency index

    float a1 = a[j], a2 = a[j + HALF];
    float b1 = b[j], b2 = b[j + HALF];
    float P = a1 * b1 + a2 * b2;
    float Q = a1 * b2 - a2 * b1;
    // f_j = 10000^(-j/64) = 2^(-j * log2(10000)/64)
    float f = exp2f(-0.20762050593046014f * (float)j);
    float s, c;
    sincosf((float)d * f, &s, &c);   // ONE accurate sincos per thread
    float sP = P * c;                // even in d
    float sQ = Q * s;                // odd  in d

    #pragma unroll
    for (int off = 32; off > 0; off >>= 1) {
        sP += __shfl_down(sP, off, 64);
        sQ += __shfl_down(sQ, off, 64);
    }
    if (lane == 0) {
        g[GOFF + d] = sP + sQ;
        g[GOFF - d] = sP - sQ;   // d=0 double-write is harmless
    }
}

__global__ __launch_bounds__(256) void fill_out_kernel(
    const float* __restrict__ g, float* __restrict__ out) {
    __shared__ float lds[1024];
    const unsigned b  = blockIdx.x;
    const unsigned m  = b >> 3;            // row
    const unsigned N0 = (b & 7u) << 10;    // first of this block's 1024 cols
    const unsigned t  = threadIdx.x;

    // Window: out[m, N0+c] = g[(GOFF + m - N0) - c], c in [0,1024).
    // Stage ascending (coalesced), write reversed (stride -1: conflict-free):
    //   lds[c] = g[hi - c]  where hi = GOFF + m - N0, lo = hi - 1023.
    const int lo = (int)(GOFF + m) - (int)N0 - 1023;   // = 7168 + m - N0, >= 0
    #pragma unroll
    for (int r = 0; r < 4; ++r) {
        int j = r * 256 + (int)t;
        lds[1023 - j] = g[lo + j];
    }
    __syncthreads();

    const unsigned c0 = t << 2;            // 16B-aligned -> ds_read_b128
    float4 v = *reinterpret_cast<const float4*>(&lds[c0]);
    *reinterpret_cast<float4*>(out + (size_t)m * CSEQ + N0 + c0) = v;
}

extern "C" void kernel_launch(void* const* d_in, const int* in_sizes, int n_in,
                              void* d_out, int out_size, void* d_ws, size_t ws_size,
                              hipStream_t stream) {
    const float* a = (const float*)d_in[0];
    const float* b = (const float*)d_in[1];
    // d_in[2] is the scalar c = 8192 (fixed by setup_inputs; hardcoded).
    float* g   = (float*)d_ws;     // 16383 * 4 B = 64 KiB of workspace
    float* out = (float*)d_out;    // 8192 x 8192 f32

    compute_g_kernel<<<CSEQ / 4 / 1, 256, 0, stream>>>(a, b, g);  // 2048 blocks x 4 waves

    fill_out_kernel<<<CSEQ * 8, 256, 0, stream>>>(g, out);        // 65536 blocks
}